// Round 17
// baseline (339.735 us; speedup 1.0000x reference)
//
#include <hip/hip_runtime.h>

#define D 64

typedef __attribute__((ext_vector_type(8))) short short8;
typedef __attribute__((ext_vector_type(4))) float f32x4;

__device__ __forceinline__ ushort f2b(float f) {
    union { float f; unsigned u; } x; x.f = f;
    unsigned r = x.u + 0x7FFFu + ((x.u >> 16) & 1u);   // RNE to bf16
    return (ushort)(r >> 16);
}
__device__ __forceinline__ float b2f(ushort u) {
    union { float f; unsigned u; } x; x.u = ((unsigned)u) << 16;
    return x.f;
}
__device__ __forceinline__ short8 pack8(float4 a, float4 b) {
    short8 r;
    r[0] = (short)f2b(a.x); r[1] = (short)f2b(a.y); r[2] = (short)f2b(a.z); r[3] = (short)f2b(a.w);
    r[4] = (short)f2b(b.x); r[5] = (short)f2b(b.y); r[6] = (short)f2b(b.z); r[7] = (short)f2b(b.w);
    return r;
}

#define LDA 72   // bf16 row stride for 64-wide LDS tiles (round-2 proven)

// ---------------------------------------------------------------------------
// fused_front: blocks [0, NPB)      -> node_proj + nfp via MFMA (64 rows/blk)
//              blocks [NPB,NPB+HB)  -> dst histogram
//              block  NPB+HB        -> Wcomb/bias2 setup
// ---------------------------------------------------------------------------
__global__ __launch_bounds__(256) void fused_front_kernel(
    const float* __restrict__ nf, const float* __restrict__ Wn,
    const float* __restrict__ bias, const float* __restrict__ Wd,   // full W_dense
    float* __restrict__ out, ushort* __restrict__ nfp_b, int N,
    const int* __restrict__ dst, int* __restrict__ deg_i, int E,
    const float* __restrict__ W_edge, const float* __restrict__ b_dense,
    const float* __restrict__ bias_edge, ushort* __restrict__ Wcomb_b,
    float* __restrict__ bias2, int NPB, int HB)
{
    __shared__ ushort Bn[64 * LDA];   // bf16 W_node  [n][k]   9216 B
    __shared__ ushort Bd[64 * LDA];   // bf16 0.5*Wd_bot [n][k] 9216 B
    __shared__ ushort Vs[64 * LDA];   // bf16 relu(nf@Wn+b)     9216 B
    const int tid = threadIdx.x;
    const int bid = blockIdx.x;

    if (bid < NPB) {
        const long row0 = (long)bid * 64;
        const int w = tid >> 6, lane = tid & 63;
        const int lr = lane & 15, g = lane >> 4;
        const bool odd = lane & 1;

        {   // stage both weight tables (transpose to [n][k], bf16)
            int k = tid >> 2, n0 = (tid & 3) * 16;
            const float4* wr = (const float4*)(Wn + (long)k * D + n0);
            float4 v0 = wr[0], v1 = wr[1], v2 = wr[2], v3 = wr[3];
            float vs[16] = {v0.x, v0.y, v0.z, v0.w, v1.x, v1.y, v1.z, v1.w,
                            v2.x, v2.y, v2.z, v2.w, v3.x, v3.y, v3.z, v3.w};
            #pragma unroll
            for (int j = 0; j < 16; ++j) Bn[(n0 + j) * LDA + k] = f2b(vs[j]);
            const float4* wd = (const float4*)(Wd + (long)(D + k) * D + n0);
            float4 u0 = wd[0], u1 = wd[1], u2 = wd[2], u3 = wd[3];
            float us[16] = {u0.x, u0.y, u0.z, u0.w, u1.x, u1.y, u1.z, u1.w,
                            u2.x, u2.y, u2.z, u2.w, u3.x, u3.y, u3.z, u3.w};
            #pragma unroll
            for (int j = 0; j < 16; ++j) Bd[(n0 + j) * LDA + k] = f2b(0.5f * us[j]);
        }

        // A-frags from global nf rows
        long era = row0 + 16 * w + lr; if (era >= N) era = N - 1;
        const float4* ap = (const float4*)(nf + era * D);
        float4 v0 = ap[2 * g], v1 = ap[2 * g + 1];
        float4 v2 = ap[8 + 2 * g], v3 = ap[8 + 2 * g + 1];
        short8 a0 = pack8(v0, v1), a1 = pack8(v2, v3);
        __syncthreads();

        // GEMM1: nf @ W_node
        f32x4 acc[4];
        #pragma unroll
        for (int t = 0; t < 4; ++t) {
            f32x4 z = {0.f, 0.f, 0.f, 0.f};
            short8 b0 = *(const short8*)&Bn[(16 * t + lr) * LDA + 8 * g];
            short8 b1 = *(const short8*)&Bn[(16 * t + lr) * LDA + 32 + 8 * g];
            z = __builtin_amdgcn_mfma_f32_16x16x32_bf16(a0, b0, z, 0, 0, 0);
            z = __builtin_amdgcn_mfma_f32_16x16x32_bf16(a1, b1, z, 0, 0, 0);
            acc[t] = z;
        }
        // epilogue1: relu+bias -> f32 out store + bf16 Vs bounce
        #pragma unroll
        for (int t = 0; t < 4; ++t) {
            int c = 16 * t + lr;
            float bb = bias[c];
            #pragma unroll
            for (int reg = 0; reg < 4; ++reg) {
                int r = 16 * w + 4 * g + reg;
                float v = fmaxf(acc[t][reg] + bb, 0.f);
                long rg = row0 + r;
                if (rg < N) out[rg * D + c] = v;
                Vs[r * LDA + c] = f2b(v);
            }
        }
        __syncthreads();

        // GEMM2: Vs @ (0.5*Wd_bot)
        short8 c0 = *(const short8*)&Vs[(16 * w + lr) * LDA + 8 * g];
        short8 c1 = *(const short8*)&Vs[(16 * w + lr) * LDA + 32 + 8 * g];
        f32x4 acc2[4];
        #pragma unroll
        for (int t = 0; t < 4; ++t) {
            f32x4 z = {0.f, 0.f, 0.f, 0.f};
            short8 b0 = *(const short8*)&Bd[(16 * t + lr) * LDA + 8 * g];
            short8 b1 = *(const short8*)&Bd[(16 * t + lr) * LDA + 32 + 8 * g];
            z = __builtin_amdgcn_mfma_f32_16x16x32_bf16(c0, b0, z, 0, 0, 0);
            z = __builtin_amdgcn_mfma_f32_16x16x32_bf16(c1, b1, z, 0, 0, 0);
            acc2[t] = z;
        }
        // packed bf16 nfp store
        const int rb = 16 * w + 4 * g + (odd ? 2 : 0);
        long e0 = row0 + rb, e1 = row0 + rb + 1;
        #pragma unroll
        for (int t = 0; t < 4; ++t) {
            float p0 = __shfl_xor(acc2[t][0], 1, 64);
            float p1 = __shfl_xor(acc2[t][1], 1, 64);
            float p2 = __shfl_xor(acc2[t][2], 1, 64);
            float p3 = __shfl_xor(acc2[t][3], 1, 64);
            float lo0, hi0, lo1, hi1;
            if (odd) { lo0 = p2; hi0 = acc2[t][2]; lo1 = p3; hi1 = acc2[t][3]; }
            else     { lo0 = acc2[t][0]; hi0 = p0; lo1 = acc2[t][1]; hi1 = p1; }
            int cbase = 16 * t + (lr & ~1);
            unsigned dw0 = ((unsigned)f2b(hi0) << 16) | (unsigned)f2b(lo0);
            unsigned dw1 = ((unsigned)f2b(hi1) << 16) | (unsigned)f2b(lo1);
            if (e0 < N) *(unsigned*)(nfp_b + e0 * D + cbase) = dw0;
            if (e1 < N) *(unsigned*)(nfp_b + e1 * D + cbase) = dw1;
        }
    } else if (bid < NPB + HB) {
        int i = (bid - NPB) * 256 + tid;
        if (i < E) atomicAdd(deg_i + dst[i], 1);
    } else {
        // setup: Wcomb_b[n*64+k] = bf16((W_edge @ Wd_top)[k][n]); bias2
        for (int idx = tid; idx < D * D; idx += 256) {
            int k = idx >> 6, n = idx & 63;
            float s = 0.f;
            #pragma unroll 8
            for (int j = 0; j < D; ++j)
                s = fmaf(W_edge[k * D + j], Wd[j * D + n], s);
            Wcomb_b[n * D + k] = f2b(s);
        }
        if (tid < D) bias2[tid] = b_dense[tid] + bias_edge[tid];
    }
}

// ---------------------------------------------------------------------------
// Counting sort by dst: scanA/scanB; scatter computes
// slot = pos[dv] + bsum[dv>>8] + cnt[dv]++ and writes split arrays:
// sorted_eid[slot] = eid (for efp_mfma), sorted_ds[slot] = (dv, sv) (for final).
// ---------------------------------------------------------------------------
__global__ __launch_bounds__(256) void scanA_kernel(
    const int* __restrict__ deg_i, int* __restrict__ pos,
    int* __restrict__ bsum, int N)
{
    __shared__ int s[256];
    const int tid = threadIdx.x;
    const int i = blockIdx.x * 256 + tid;
    int v = (i < N) ? deg_i[i] : 0;
    s[tid] = v;
    __syncthreads();
    #pragma unroll
    for (int off = 1; off < 256; off <<= 1) {
        int t = (tid >= off) ? s[tid - off] : 0;
        __syncthreads();
        s[tid] += t;
        __syncthreads();
    }
    if (i < N) pos[i] = s[tid] - v;          // block-local exclusive
    if (tid == 255) bsum[blockIdx.x] = s[255];
}

__global__ __launch_bounds__(256) void scanB_kernel(int* __restrict__ bsum, int NB)
{
    __shared__ int s[256];
    const int tid = threadIdx.x;
    int v = (tid < NB) ? bsum[tid] : 0;
    s[tid] = v;
    __syncthreads();
    #pragma unroll
    for (int off = 1; off < 256; off <<= 1) {
        int t = (tid >= off) ? s[tid - off] : 0;
        __syncthreads();
        s[tid] += t;
        __syncthreads();
    }
    if (tid < NB) bsum[tid] = s[tid] - v;    // exclusive
}

__global__ __launch_bounds__(256) void scatter_kernel(
    const int* __restrict__ dst, const int* __restrict__ src,
    const int* __restrict__ pos, const int* __restrict__ bsum,
    int* __restrict__ cnt, int* __restrict__ sorted_eid,
    int2* __restrict__ sorted_ds, int E)
{
    int i = blockIdx.x * 256 + threadIdx.x;
    if (i < E) {
        int dv = dst[i];
        int slot = pos[dv] + bsum[dv >> 8] + atomicAdd(cnt + dv, 1);
        sorted_eid[slot] = i;
        sorted_ds[slot] = make_int2(dv, src[i]);
    }
}

// ---------------------------------------------------------------------------
// efp_mfma: 256 dst-sorted slots per block (4 MFMA tiles), 4 waves.
// Pure: gather ef rows -> MFMA -> SEQUENTIAL packed bf16 store to efp[slot].
// No LDS, no barrier, no atomics (segment sum moved to segmean_ndp).
// ---------------------------------------------------------------------------
#define SEG_ROWS 256
__global__ __launch_bounds__(256) void efp_mfma_kernel(
    const float* __restrict__ ef, const int* __restrict__ sorted_eid,
    const ushort* __restrict__ Wt, ushort* __restrict__ efp, int E)
{
    const int tid = threadIdx.x;
    const long s0 = (long)blockIdx.x * SEG_ROWS;
    const int w = tid >> 6, lane = tid & 63;
    const int lr = lane & 15, g = lane >> 4;
    const bool odd = lane & 1;

    long gde[4];
    #pragma unroll
    for (int tt = 0; tt < 4; ++tt) {
        long s = s0 + 64 * tt + 16 * w + lr;
        if (s >= E) s = E - 1;
        gde[tt] = (long)sorted_eid[s];
    }
    float4 va[4][4];
    #pragma unroll
    for (int tt = 0; tt < 4; ++tt) {
        const float4* ap = (const float4*)(ef + gde[tt] * D);
        va[tt][0] = ap[2 * g];     va[tt][1] = ap[2 * g + 1];
        va[tt][2] = ap[8 + 2 * g]; va[tt][3] = ap[8 + 2 * g + 1];
    }

    short8 bf0[4], bf1[4];
    #pragma unroll
    for (int t = 0; t < 4; ++t) {
        bf0[t] = *(const short8*)&Wt[(16 * t + lr) * D + 8 * g];
        bf1[t] = *(const short8*)&Wt[(16 * t + lr) * D + 32 + 8 * g];
    }

    #pragma unroll
    for (int tt = 0; tt < 4; ++tt) {
        short8 a0 = pack8(va[tt][0], va[tt][1]);
        short8 a1 = pack8(va[tt][2], va[tt][3]);
        f32x4 acc[4];
        #pragma unroll
        for (int t = 0; t < 4; ++t) {
            f32x4 z = {0.f, 0.f, 0.f, 0.f};
            z = __builtin_amdgcn_mfma_f32_16x16x32_bf16(a0, bf0[t], z, 0, 0, 0);
            z = __builtin_amdgcn_mfma_f32_16x16x32_bf16(a1, bf1[t], z, 0, 0, 0);
            acc[t] = z;
        }

        const int rb = 64 * tt + 16 * w + 4 * g + (odd ? 2 : 0);
        long sl0 = s0 + rb, sl1 = s0 + rb + 1;
        #pragma unroll
        for (int t = 0; t < 4; ++t) {
            float p0 = __shfl_xor(acc[t][0], 1, 64);
            float p1 = __shfl_xor(acc[t][1], 1, 64);
            float p2 = __shfl_xor(acc[t][2], 1, 64);
            float p3 = __shfl_xor(acc[t][3], 1, 64);
            float lo0, hi0, lo1, hi1;
            if (odd) { lo0 = p2; hi0 = acc[t][2]; lo1 = p3; hi1 = acc[t][3]; }
            else     { lo0 = acc[t][0]; hi0 = p0; lo1 = acc[t][1]; hi1 = p1; }
            int cbase = 16 * t + (lr & ~1);
            unsigned dw0 = ((unsigned)f2b(hi0) << 16) | (unsigned)f2b(lo0);
            unsigned dw1 = ((unsigned)f2b(hi1) << 16) | (unsigned)f2b(lo1);
            if (sl0 < E) *(unsigned*)(efp + sl0 * D + cbase) = dw0;
            if (sl1 < E) *(unsigned*)(efp + sl1 * D + cbase) = dw1;
        }
    }
}

// ---------------------------------------------------------------------------
// segmean_ndp: one wave per node. Node n's edges occupy the CONTIGUOUS slot
// run [p0, p0+deg) in efp (dst-sorted layout) -> sequential reads, no atomics.
// ndp_b[n] = bf16( mean(efp run) + nfp[n] ).  Lanes: rp = lane>>5 (row parity),
// dc = lane&31 (dword col); 2 rows per iteration; parity combine via shfl.
// ---------------------------------------------------------------------------
__global__ __launch_bounds__(256) void segmean_ndp_kernel(
    const ushort* __restrict__ efp, const int* __restrict__ pos,
    const int* __restrict__ bsum, const int* __restrict__ deg_i,
    const ushort* __restrict__ nfp_b, ushort* __restrict__ ndp_b, int N)
{
    const int w = threadIdx.x >> 6, lane = threadIdx.x & 63;
    const int n = blockIdx.x * 4 + w;
    if (n >= N) return;
    const int rp = lane >> 5, dc = lane & 31;
    const long p0 = (long)pos[n] + bsum[n >> 8];
    const int d = deg_i[n];

    float seg0 = 0.f, seg1 = 0.f;
    for (int i = rp; i < d; i += 2) {
        unsigned u = *(const unsigned*)(efp + (p0 + i) * D + dc * 2);
        seg0 += b2f((ushort)(u & 0xffff));
        seg1 += b2f((ushort)(u >> 16));
    }
    seg0 += __shfl_xor(seg0, 32, 64);
    seg1 += __shfl_xor(seg1, 32, 64);

    if (rp == 0) {
        float inv = 1.0f / fmaxf((float)d, 1.0f);
        unsigned nu = *(const unsigned*)(nfp_b + (long)n * D + dc * 2);
        float r0 = seg0 * inv + b2f((ushort)(nu & 0xffff));
        float r1 = seg1 * inv + b2f((ushort)(nu >> 16));
        unsigned dw = ((unsigned)f2b(r1) << 16) | (unsigned)f2b(r0);
        *(unsigned*)(ndp_b + (long)n * D + dc * 2) = dw;
    }
}

// ---------------------------------------------------------------------------
// final (slot order): for slot s, eid = sorted_eid[s], (dv,sv) = sorted_ds[s];
// out[eid] = relu(efp[s] + ndp[dv] + nfp[sv] + bias2).
// efp read sequential (L3-hot); ndp[dv] monotone; nfp[sv] random (L2-resident).
// ---------------------------------------------------------------------------
__global__ __launch_bounds__(256) void final_kernel(
    const ushort* __restrict__ efp, const int* __restrict__ sorted_eid,
    const int2* __restrict__ sorted_ds, const ushort* __restrict__ ndp_b,
    const ushort* __restrict__ nfp_b, const float* __restrict__ bias2,
    float* __restrict__ out, int E)
{
    long idx = (long)blockIdx.x * 256 + threadIdx.x;
    long s = idx >> 2;
    int q = (int)(idx & 3);
    if (s >= E) return;
    long eid = sorted_eid[s];
    int2 ds = sorted_ds[s];
    int dv = ds.x, sv = ds.y;

    const short8* ep = (const short8*)(efp + s * D + q * 16);
    const short8* np = (const short8*)(ndp_b + (long)dv * D + q * 16);
    const short8* sp = (const short8*)(nfp_b + (long)sv * D + q * 16);
    short8 e0 = ep[0], e1 = ep[1];
    short8 n0 = np[0], n1 = np[1];
    short8 s0 = sp[0], s1 = sp[1];
    const float4* bp = (const float4*)(bias2 + q * 16);
    float4 b0 = bp[0], b1 = bp[1], b2 = bp[2], b3 = bp[3];

    float r[16];
    #pragma unroll
    for (int j = 0; j < 8; ++j) {
        r[j]     = b2f((ushort)e0[j]) + b2f((ushort)n0[j]) + b2f((ushort)s0[j]);
        r[8 + j] = b2f((ushort)e1[j]) + b2f((ushort)n1[j]) + b2f((ushort)s1[j]);
    }
    float4* op = (float4*)(out + eid * D + q * 16);
    op[0] = make_float4(fmaxf(r[0] + b0.x, 0.f), fmaxf(r[1] + b0.y, 0.f),
                        fmaxf(r[2] + b0.z, 0.f), fmaxf(r[3] + b0.w, 0.f));
    op[1] = make_float4(fmaxf(r[4] + b1.x, 0.f), fmaxf(r[5] + b1.y, 0.f),
                        fmaxf(r[6] + b1.z, 0.f), fmaxf(r[7] + b1.w, 0.f));
    op[2] = make_float4(fmaxf(r[8] + b2.x, 0.f), fmaxf(r[9] + b2.y, 0.f),
                        fmaxf(r[10] + b2.z, 0.f), fmaxf(r[11] + b2.w, 0.f));
    op[3] = make_float4(fmaxf(r[12] + b3.x, 0.f), fmaxf(r[13] + b3.y, 0.f),
                        fmaxf(r[14] + b3.z, 0.f), fmaxf(r[15] + b3.w, 0.f));
}

// ---------------------------------------------------------------------------
extern "C" void kernel_launch(void* const* d_in, const int* in_sizes, int n_in,
                              void* d_out, int out_size, void* d_ws, size_t ws_size,
                              hipStream_t stream) {
    const float* nf        = (const float*)d_in[0];
    const float* ef        = (const float*)d_in[1];
    const int*   src       = (const int*)d_in[2];
    const int*   dst       = (const int*)d_in[3];
    const float* W_node    = (const float*)d_in[4];
    const float* W_edge    = (const float*)d_in[5];
    const float* bias_node = (const float*)d_in[6];
    const float* bias_edge = (const float*)d_in[7];
    const float* W_dense   = (const float*)d_in[8];
    const float* b_dense   = (const float*)d_in[9];

    const int N = in_sizes[0] / D;
    const int E = in_sizes[1] / D;
    const int NB = (N + 255) / 256;
    const int NPB = (N + 63) / 64;
    const int HB = (E + 255) / 256;

    float* nf_out = (float*)d_out;
    float* ef_out = (float*)d_out + (size_t)N * D;

    // ws layout: [zeroed: deg_i, cnt] then the rest
    char* p = (char*)d_ws;
    int*    deg_i    = (int*)p;     p += (size_t)N * 4;           // zeroed
    int*    cnt      = (int*)p;     p += (size_t)N * 4;           // zeroed
    size_t  zbytes   = (size_t)(p - (char*)d_ws);
    int*    pos      = (int*)p;     p += (size_t)N * 4;
    int*    bsum     = (int*)p;     p += 256 * 4;
    int*    sorted_eid=(int*)p;     p += (size_t)E * 4;           // 3.2 MB
    int2*   sorted_ds= (int2*)p;    p += (size_t)E * 8;           // 6.4 MB
    ushort* nfp_b    = (ushort*)p;  p += (size_t)N * D * 2;
    ushort* ndp_b    = (ushort*)p;  p += (size_t)N * D * 2;
    ushort* Wcomb_b  = (ushort*)p;  p += D * D * 2;
    float*  bias2    = (float*)p;   p += 256;
    ushort* efp      = (ushort*)p;  /* E*D*2 = 102.4 MB, slot order */

    hipMemsetAsync(d_ws, 0, zbytes, stream);

    fused_front_kernel<<<NPB + HB + 1, 256, 0, stream>>>(
        nf, W_node, bias_node, W_dense, nf_out, nfp_b, N,
        dst, deg_i, E, W_edge, b_dense, bias_edge, Wcomb_b, bias2, NPB, HB);
    scanA_kernel<<<NB, 256, 0, stream>>>(deg_i, pos, bsum, N);
    scanB_kernel<<<1, 256, 0, stream>>>(bsum, NB);
    scatter_kernel<<<(E + 255) / 256, 256, 0, stream>>>(dst, src, pos, bsum, cnt,
                                                        sorted_eid, sorted_ds, E);
    efp_mfma_kernel<<<(E + SEG_ROWS - 1) / SEG_ROWS, 256, 0, stream>>>(
        ef, sorted_eid, Wcomb_b, efp, E);
    segmean_ndp_kernel<<<(N + 3) / 4, 256, 0, stream>>>(
        efp, pos, bsum, deg_i, nfp_b, ndp_b, N);
    final_kernel<<<(int)(((size_t)E * 4 + 255) / 256), 256, 0, stream>>>(
        efp, sorted_eid, sorted_ds, ndp_b, nfp_b, bias2, ef_out, E);
}

// Round 18
// 336.057 us; speedup vs baseline: 1.0109x; 1.0109x over previous
//
#include <hip/hip_runtime.h>

#define D 64

typedef __attribute__((ext_vector_type(8))) short short8;
typedef __attribute__((ext_vector_type(4))) float f32x4;

__device__ __forceinline__ ushort f2b(float f) {
    union { float f; unsigned u; } x; x.f = f;
    unsigned r = x.u + 0x7FFFu + ((x.u >> 16) & 1u);   // RNE to bf16
    return (ushort)(r >> 16);
}
__device__ __forceinline__ float b2f(ushort u) {
    union { float f; unsigned u; } x; x.u = ((unsigned)u) << 16;
    return x.f;
}
__device__ __forceinline__ short8 pack8(float4 a, float4 b) {
    short8 r;
    r[0] = (short)f2b(a.x); r[1] = (short)f2b(a.y); r[2] = (short)f2b(a.z); r[3] = (short)f2b(a.w);
    r[4] = (short)f2b(b.x); r[5] = (short)f2b(b.y); r[6] = (short)f2b(b.z); r[7] = (short)f2b(b.w);
    return r;
}

#define LDA 72   // bf16 row stride for 64-wide LDS tiles (round-2 proven)

// ---------------------------------------------------------------------------
// fused_front: blocks [0, NPB)      -> node_proj + nfp via MFMA (64 rows/blk)
//              blocks [NPB,NPB+HB)  -> dst histogram
//              block  NPB+HB        -> Wcomb/bias2 setup
// ---------------------------------------------------------------------------
__global__ __launch_bounds__(256) void fused_front_kernel(
    const float* __restrict__ nf, const float* __restrict__ Wn,
    const float* __restrict__ bias, const float* __restrict__ Wd,   // full W_dense
    float* __restrict__ out, ushort* __restrict__ nfp_b, int N,
    const int* __restrict__ dst, int* __restrict__ deg_i, int E,
    const float* __restrict__ W_edge, const float* __restrict__ b_dense,
    const float* __restrict__ bias_edge, ushort* __restrict__ Wcomb_b,
    float* __restrict__ bias2, int NPB, int HB)
{
    __shared__ ushort Bn[64 * LDA];   // bf16 W_node  [n][k]   9216 B
    __shared__ ushort Bd[64 * LDA];   // bf16 0.5*Wd_bot [n][k] 9216 B
    __shared__ ushort Vs[64 * LDA];   // bf16 relu(nf@Wn+b)     9216 B
    const int tid = threadIdx.x;
    const int bid = blockIdx.x;

    if (bid < NPB) {
        const long row0 = (long)bid * 64;
        const int w = tid >> 6, lane = tid & 63;
        const int lr = lane & 15, g = lane >> 4;
        const bool odd = lane & 1;

        {   // stage both weight tables (transpose to [n][k], bf16)
            int k = tid >> 2, n0 = (tid & 3) * 16;
            const float4* wr = (const float4*)(Wn + (long)k * D + n0);
            float4 v0 = wr[0], v1 = wr[1], v2 = wr[2], v3 = wr[3];
            float vs[16] = {v0.x, v0.y, v0.z, v0.w, v1.x, v1.y, v1.z, v1.w,
                            v2.x, v2.y, v2.z, v2.w, v3.x, v3.y, v3.z, v3.w};
            #pragma unroll
            for (int j = 0; j < 16; ++j) Bn[(n0 + j) * LDA + k] = f2b(vs[j]);
            const float4* wd = (const float4*)(Wd + (long)(D + k) * D + n0);
            float4 u0 = wd[0], u1 = wd[1], u2 = wd[2], u3 = wd[3];
            float us[16] = {u0.x, u0.y, u0.z, u0.w, u1.x, u1.y, u1.z, u1.w,
                            u2.x, u2.y, u2.z, u2.w, u3.x, u3.y, u3.z, u3.w};
            #pragma unroll
            for (int j = 0; j < 16; ++j) Bd[(n0 + j) * LDA + k] = f2b(0.5f * us[j]);
        }

        // A-frags from global nf rows
        long era = row0 + 16 * w + lr; if (era >= N) era = N - 1;
        const float4* ap = (const float4*)(nf + era * D);
        float4 v0 = ap[2 * g], v1 = ap[2 * g + 1];
        float4 v2 = ap[8 + 2 * g], v3 = ap[8 + 2 * g + 1];
        short8 a0 = pack8(v0, v1), a1 = pack8(v2, v3);
        __syncthreads();

        // GEMM1: nf @ W_node
        f32x4 acc[4];
        #pragma unroll
        for (int t = 0; t < 4; ++t) {
            f32x4 z = {0.f, 0.f, 0.f, 0.f};
            short8 b0 = *(const short8*)&Bn[(16 * t + lr) * LDA + 8 * g];
            short8 b1 = *(const short8*)&Bn[(16 * t + lr) * LDA + 32 + 8 * g];
            z = __builtin_amdgcn_mfma_f32_16x16x32_bf16(a0, b0, z, 0, 0, 0);
            z = __builtin_amdgcn_mfma_f32_16x16x32_bf16(a1, b1, z, 0, 0, 0);
            acc[t] = z;
        }
        // epilogue1: relu+bias -> f32 out store + bf16 Vs bounce
        #pragma unroll
        for (int t = 0; t < 4; ++t) {
            int c = 16 * t + lr;
            float bb = bias[c];
            #pragma unroll
            for (int reg = 0; reg < 4; ++reg) {
                int r = 16 * w + 4 * g + reg;
                float v = fmaxf(acc[t][reg] + bb, 0.f);
                long rg = row0 + r;
                if (rg < N) out[rg * D + c] = v;
                Vs[r * LDA + c] = f2b(v);
            }
        }
        __syncthreads();

        // GEMM2: Vs @ (0.5*Wd_bot)
        short8 c0 = *(const short8*)&Vs[(16 * w + lr) * LDA + 8 * g];
        short8 c1 = *(const short8*)&Vs[(16 * w + lr) * LDA + 32 + 8 * g];
        f32x4 acc2[4];
        #pragma unroll
        for (int t = 0; t < 4; ++t) {
            f32x4 z = {0.f, 0.f, 0.f, 0.f};
            short8 b0 = *(const short8*)&Bd[(16 * t + lr) * LDA + 8 * g];
            short8 b1 = *(const short8*)&Bd[(16 * t + lr) * LDA + 32 + 8 * g];
            z = __builtin_amdgcn_mfma_f32_16x16x32_bf16(c0, b0, z, 0, 0, 0);
            z = __builtin_amdgcn_mfma_f32_16x16x32_bf16(c1, b1, z, 0, 0, 0);
            acc2[t] = z;
        }
        // packed bf16 nfp store
        const int rb = 16 * w + 4 * g + (odd ? 2 : 0);
        long e0 = row0 + rb, e1 = row0 + rb + 1;
        #pragma unroll
        for (int t = 0; t < 4; ++t) {
            float p0 = __shfl_xor(acc2[t][0], 1, 64);
            float p1 = __shfl_xor(acc2[t][1], 1, 64);
            float p2 = __shfl_xor(acc2[t][2], 1, 64);
            float p3 = __shfl_xor(acc2[t][3], 1, 64);
            float lo0, hi0, lo1, hi1;
            if (odd) { lo0 = p2; hi0 = acc2[t][2]; lo1 = p3; hi1 = acc2[t][3]; }
            else     { lo0 = acc2[t][0]; hi0 = p0; lo1 = acc2[t][1]; hi1 = p1; }
            int cbase = 16 * t + (lr & ~1);
            unsigned dw0 = ((unsigned)f2b(hi0) << 16) | (unsigned)f2b(lo0);
            unsigned dw1 = ((unsigned)f2b(hi1) << 16) | (unsigned)f2b(lo1);
            if (e0 < N) *(unsigned*)(nfp_b + e0 * D + cbase) = dw0;
            if (e1 < N) *(unsigned*)(nfp_b + e1 * D + cbase) = dw1;
        }
    } else if (bid < NPB + HB) {
        int i = (bid - NPB) * 256 + tid;
        if (i < E) atomicAdd(deg_i + dst[i], 1);
    } else {
        // setup: Wcomb_b[n*64+k] = bf16((W_edge @ Wd_top)[k][n]); bias2
        for (int idx = tid; idx < D * D; idx += 256) {
            int k = idx >> 6, n = idx & 63;
            float s = 0.f;
            #pragma unroll 8
            for (int j = 0; j < D; ++j)
                s = fmaf(W_edge[k * D + j], Wd[j * D + n], s);
            Wcomb_b[n * D + k] = f2b(s);
        }
        if (tid < D) bias2[tid] = b_dense[tid] + bias_edge[tid];
    }
}

// ---------------------------------------------------------------------------
// Counting sort by dst: (hist in fused_front) -> scanA/scanB -> scatter.
// scanC folded into scatter: slot = pos[dv] + bsum[dv>>8] + cnt[dv]++.
// sorted_eds[slot] = (eid, dst, src, 0).
// ---------------------------------------------------------------------------
__global__ __launch_bounds__(256) void scanA_kernel(
    const int* __restrict__ deg_i, int* __restrict__ pos,
    int* __restrict__ bsum, int N)
{
    __shared__ int s[256];
    const int tid = threadIdx.x;
    const int i = blockIdx.x * 256 + tid;
    int v = (i < N) ? deg_i[i] : 0;
    s[tid] = v;
    __syncthreads();
    #pragma unroll
    for (int off = 1; off < 256; off <<= 1) {
        int t = (tid >= off) ? s[tid - off] : 0;
        __syncthreads();
        s[tid] += t;
        __syncthreads();
    }
    if (i < N) pos[i] = s[tid] - v;          // block-local exclusive
    if (tid == 255) bsum[blockIdx.x] = s[255];
}

__global__ __launch_bounds__(256) void scanB_kernel(int* __restrict__ bsum, int NB)
{
    __shared__ int s[256];
    const int tid = threadIdx.x;
    int v = (tid < NB) ? bsum[tid] : 0;
    s[tid] = v;
    __syncthreads();
    #pragma unroll
    for (int off = 1; off < 256; off <<= 1) {
        int t = (tid >= off) ? s[tid - off] : 0;
        __syncthreads();
        s[tid] += t;
        __syncthreads();
    }
    if (tid < NB) bsum[tid] = s[tid] - v;    // exclusive
}

__global__ __launch_bounds__(256) void scatter_kernel(
    const int* __restrict__ dst, const int* __restrict__ src,
    const int* __restrict__ pos, const int* __restrict__ bsum,
    int* __restrict__ cnt, int4* __restrict__ sorted_eds, int E)
{
    int i = blockIdx.x * 256 + threadIdx.x;
    if (i < E) {
        int dv = dst[i];
        int slot = pos[dv] + bsum[dv >> 8] + atomicAdd(cnt + dv, 1);
        sorted_eds[slot] = make_int4(i, dv, src[i], 0);
    }
}

// ---------------------------------------------------------------------------
// efp_seg: 256 dst-sorted edges per block (4 MFMA tiles), 4 waves.
// ef-row gathers (the only permutation) -> MFMA -> packed bf16 dwords
// stored to efp in SLOT ORDER (sequential) AND bf16 LDS tile (stride 34);
// one barrier; parallel segment walk -> f32 atomics into nb_sum.
// ---------------------------------------------------------------------------
#define SEG_ROWS 256
#define SLSTR 34
__global__ __launch_bounds__(256) void efp_seg_kernel(
    const float* __restrict__ ef, const int4* __restrict__ sorted_eds,
    const ushort* __restrict__ Wt, ushort* __restrict__ efp,
    float* __restrict__ nb_sum, int E)
{
    __shared__ unsigned Slds[SEG_ROWS * SLSTR];   // 34816 B
    __shared__ int dsts[SEG_ROWS];                // 1024 B
    const int tid = threadIdx.x;
    const long s0 = (long)blockIdx.x * SEG_ROWS;

    const int w = tid >> 6, lane = tid & 63;
    const int lr = lane & 15, g = lane >> 4;
    const bool odd = lane & 1;

    long gde[4];
    #pragma unroll
    for (int tt = 0; tt < 4; ++tt) {
        long s = s0 + 64 * tt + 16 * w + lr;
        if (s >= E) s = E - 1;
        gde[tt] = (long)sorted_eds[s].x;
    }
    float4 va[4][4];
    #pragma unroll
    for (int tt = 0; tt < 4; ++tt) {
        const float4* ap = (const float4*)(ef + gde[tt] * D);
        va[tt][0] = ap[2 * g];     va[tt][1] = ap[2 * g + 1];
        va[tt][2] = ap[8 + 2 * g]; va[tt][3] = ap[8 + 2 * g + 1];
    }
    {
        long s = s0 + tid;
        dsts[tid] = (s < E) ? sorted_eds[s].y : -1;
    }

    short8 bf0[4], bf1[4];
    #pragma unroll
    for (int t = 0; t < 4; ++t) {
        bf0[t] = *(const short8*)&Wt[(16 * t + lr) * D + 8 * g];
        bf1[t] = *(const short8*)&Wt[(16 * t + lr) * D + 32 + 8 * g];
    }

    #pragma unroll
    for (int tt = 0; tt < 4; ++tt) {
        short8 a0 = pack8(va[tt][0], va[tt][1]);
        short8 a1 = pack8(va[tt][2], va[tt][3]);
        f32x4 acc[4];
        #pragma unroll
        for (int t = 0; t < 4; ++t) {
            f32x4 z = {0.f, 0.f, 0.f, 0.f};
            z = __builtin_amdgcn_mfma_f32_16x16x32_bf16(a0, bf0[t], z, 0, 0, 0);
            z = __builtin_amdgcn_mfma_f32_16x16x32_bf16(a1, bf1[t], z, 0, 0, 0);
            acc[t] = z;
        }

        const int rb = 64 * tt + 16 * w + 4 * g + (odd ? 2 : 0);
        long sl0 = s0 + rb, sl1 = s0 + rb + 1;
        #pragma unroll
        for (int t = 0; t < 4; ++t) {
            float p0 = __shfl_xor(acc[t][0], 1, 64);
            float p1 = __shfl_xor(acc[t][1], 1, 64);
            float p2 = __shfl_xor(acc[t][2], 1, 64);
            float p3 = __shfl_xor(acc[t][3], 1, 64);
            float lo0, hi0, lo1, hi1;
            if (odd) { lo0 = p2; hi0 = acc[t][2]; lo1 = p3; hi1 = acc[t][3]; }
            else     { lo0 = acc[t][0]; hi0 = p0; lo1 = acc[t][1]; hi1 = p1; }
            int cbase = 16 * t + (lr & ~1);
            int dc = cbase >> 1;
            unsigned dw0 = ((unsigned)f2b(hi0) << 16) | (unsigned)f2b(lo0);
            unsigned dw1 = ((unsigned)f2b(hi1) << 16) | (unsigned)f2b(lo1);
            if (sl0 < E) *(unsigned*)(efp + sl0 * D + cbase) = dw0;
            if (sl1 < E) *(unsigned*)(efp + sl1 * D + cbase) = dw1;
            Slds[rb * SLSTR + dc]       = dw0;
            Slds[(rb + 1) * SLSTR + dc] = dw1;
        }
    }
    __syncthreads();

    {
        const int dwc = tid & 31;
        const int r0 = (tid >> 5) * 32;
        float seg0 = 0.f, seg1 = 0.f;
        int cur = dsts[r0];
        #pragma unroll 4
        for (int r = r0; r < r0 + 32; ++r) {
            int dv = dsts[r];
            unsigned u = Slds[r * SLSTR + dwc];
            if (dv != cur) {
                if (cur >= 0) {
                    atomicAdd(nb_sum + (long)cur * D + 2 * dwc, seg0);
                    atomicAdd(nb_sum + (long)cur * D + 2 * dwc + 1, seg1);
                }
                seg0 = seg1 = 0.f;
                cur = dv;
            }
            seg0 += b2f((ushort)(u & 0xffff));
            seg1 += b2f((ushort)(u >> 16));
        }
        if (cur >= 0) {
            atomicAdd(nb_sum + (long)cur * D + 2 * dwc, seg0);
            atomicAdd(nb_sum + (long)cur * D + 2 * dwc + 1, seg1);
        }
    }
}

// ---------------------------------------------------------------------------
// final (slot order, ndp fused): for slot s, (eid,dv,sv) = sorted_eds[s];
// out[eid] = relu(efp[s] + nb_sum[dv]/max(deg,1) + nfp[dv] + nfp[sv] + bias2).
// ---------------------------------------------------------------------------
__global__ __launch_bounds__(256) void final_kernel(
    const ushort* __restrict__ efp, const int4* __restrict__ sorted_eds,
    const float* __restrict__ nb_sum, const int* __restrict__ deg_i,
    const ushort* __restrict__ nfp_b, const float* __restrict__ bias2,
    float* __restrict__ out, int E)
{
    long idx = (long)blockIdx.x * 256 + threadIdx.x;
    long s = idx >> 2;
    int q = (int)(idx & 3);
    if (s >= E) return;
    int4 ed = sorted_eds[s];
    long eid = ed.x;
    int dv = ed.y, sv = ed.z;

    const short8* ep = (const short8*)(efp + s * D + q * 16);
    const float4* nb = (const float4*)(nb_sum + (long)dv * D + q * 16);
    const short8* nd = (const short8*)(nfp_b + (long)dv * D + q * 16);
    const short8* sp = (const short8*)(nfp_b + (long)sv * D + q * 16);
    short8 e0 = ep[0], e1 = ep[1];
    float4 x0 = nb[0], x1 = nb[1], x2 = nb[2], x3 = nb[3];
    short8 d0 = nd[0], d1 = nd[1];
    short8 s0 = sp[0], s1 = sp[1];
    float inv = 1.0f / fmaxf((float)deg_i[dv], 1.0f);
    const float4* bp = (const float4*)(bias2 + q * 16);
    float4 b0 = bp[0], b1 = bp[1], b2 = bp[2], b3 = bp[3];

    float xb[16] = {x0.x, x0.y, x0.z, x0.w, x1.x, x1.y, x1.z, x1.w,
                    x2.x, x2.y, x2.z, x2.w, x3.x, x3.y, x3.z, x3.w};
    float r[16];
    #pragma unroll
    for (int j = 0; j < 8; ++j) {
        r[j]     = b2f((ushort)e0[j]) + xb[j] * inv + b2f((ushort)d0[j]) + b2f((ushort)s0[j]);
        r[8 + j] = b2f((ushort)e1[j]) + xb[8 + j] * inv + b2f((ushort)d1[j]) + b2f((ushort)s1[j]);
    }
    float4* op = (float4*)(out + eid * D + q * 16);
    op[0] = make_float4(fmaxf(r[0] + b0.x, 0.f), fmaxf(r[1] + b0.y, 0.f),
                        fmaxf(r[2] + b0.z, 0.f), fmaxf(r[3] + b0.w, 0.f));
    op[1] = make_float4(fmaxf(r[4] + b1.x, 0.f), fmaxf(r[5] + b1.y, 0.f),
                        fmaxf(r[6] + b1.z, 0.f), fmaxf(r[7] + b1.w, 0.f));
    op[2] = make_float4(fmaxf(r[8] + b2.x, 0.f), fmaxf(r[9] + b2.y, 0.f),
                        fmaxf(r[10] + b2.z, 0.f), fmaxf(r[11] + b2.w, 0.f));
    op[3] = make_float4(fmaxf(r[12] + b3.x, 0.f), fmaxf(r[13] + b3.y, 0.f),
                        fmaxf(r[14] + b3.z, 0.f), fmaxf(r[15] + b3.w, 0.f));
}

// ---------------------------------------------------------------------------
extern "C" void kernel_launch(void* const* d_in, const int* in_sizes, int n_in,
                              void* d_out, int out_size, void* d_ws, size_t ws_size,
                              hipStream_t stream) {
    const float* nf        = (const float*)d_in[0];
    const float* ef        = (const float*)d_in[1];
    const int*   src       = (const int*)d_in[2];
    const int*   dst       = (const int*)d_in[3];
    const float* W_node    = (const float*)d_in[4];
    const float* W_edge    = (const float*)d_in[5];
    const float* bias_node = (const float*)d_in[6];
    const float* bias_edge = (const float*)d_in[7];
    const float* W_dense   = (const float*)d_in[8];
    const float* b_dense   = (const float*)d_in[9];

    const int N = in_sizes[0] / D;
    const int E = in_sizes[1] / D;
    const int NB = (N + 255) / 256;
    const int NPB = (N + 63) / 64;
    const int HB = (E + 255) / 256;

    float* nf_out = (float*)d_out;
    float* ef_out = (float*)d_out + (size_t)N * D;

    // ws layout: [zeroed: deg_i, nb_sum, cnt] then the rest
    char* p = (char*)d_ws;
    int*    deg_i    = (int*)p;     p += (size_t)N * 4;           // zeroed
    float*  nb_sum   = (float*)p;   p += (size_t)N * D * 4;       // zeroed, 12.8 MB
    int*    cnt      = (int*)p;     p += (size_t)N * 4;           // zeroed
    size_t  zbytes   = (size_t)(p - (char*)d_ws);
    int*    pos      = (int*)p;     p += (size_t)N * 4;
    int*    bsum     = (int*)p;     p += 256 * 4;
    int4*   sorted_eds=(int4*)p;    p += (size_t)E * 16;          // 12.8 MB
    ushort* nfp_b    = (ushort*)p;  p += (size_t)N * D * 2;
    ushort* Wcomb_b  = (ushort*)p;  p += D * D * 2;
    float*  bias2    = (float*)p;   p += 256;
    ushort* efp      = (ushort*)p;  /* E*D*2 = 102.4 MB, slot order */

    hipMemsetAsync(d_ws, 0, zbytes, stream);

    fused_front_kernel<<<NPB + HB + 1, 256, 0, stream>>>(
        nf, W_node, bias_node, W_dense, nf_out, nfp_b, N,
        dst, deg_i, E, W_edge, b_dense, bias_edge, Wcomb_b, bias2, NPB, HB);
    scanA_kernel<<<NB, 256, 0, stream>>>(deg_i, pos, bsum, N);
    scanB_kernel<<<1, 256, 0, stream>>>(bsum, NB);
    scatter_kernel<<<(E + 255) / 256, 256, 0, stream>>>(dst, src, pos, bsum, cnt,
                                                        sorted_eds, E);
    efp_seg_kernel<<<(E + SEG_ROWS - 1) / SEG_ROWS, 256, 0, stream>>>(
        ef, sorted_eds, Wcomb_b, efp, nb_sum, E);
    final_kernel<<<(int)(((size_t)E * 4 + 255) / 256), 256, 0, stream>>>(
        efp, sorted_eds, nb_sum, deg_i, nfp_b, bias2, ef_out, E);
}